// Round 5
// baseline (1902.315 us; speedup 1.0000x reference)
//
#include <hip/hip_runtime.h>
#include <hip/hip_cooperative_groups.h>

namespace cg = cooperative_groups;

// Sizes fixed by the problem.
#define TT 1653          // T
#define DD 512           // D
#define BB 2             // B
#define DE 64            // D/E
#define BEH 16           // B*E
#define TTILES 26        // ceil(T/64)
#define TPAD 1664        // T padded to multiple of 64
#define NJC 2            // ovt j-split: 26*16*2 = 832 vblocks (one grid pass)
#define SCN 2            // attn s-split: 832 vblocks (one grid pass)
#define MPSTRIDE TPAD
#define HSTRIDE ((size_t)BB * TT * DD)   // fp32 partial stride (elements)
#define GRIDN 1024       // 4 blocks/CU x 256 CUs (co-resident for grid.sync)
#define NTHR 256

typedef __attribute__((ext_vector_type(8))) short bf16x8;
typedef __attribute__((ext_vector_type(4))) float f32x4;
typedef float f32x4u  __attribute__((ext_vector_type(4), aligned(4)));  // O rows only 4B-aligned

__device__ __forceinline__ short f2bf(float f) {
    union { float f; unsigned u; } v; v.f = f;
    unsigned r = v.u + 0x7fffu + ((v.u >> 16) & 1u);   // RNE
    return (short)(r >> 16);
}
__device__ __forceinline__ unsigned pack2(float a, float b) {
    return (unsigned)(unsigned short)f2bf(a) | ((unsigned)(unsigned short)f2bf(b) << 16);
}
__device__ __forceinline__ float bf2f(short s) {
    union { unsigned u; float f; } v; v.u = ((unsigned)(unsigned short)s) << 16;
    return v.f;
}

// Raw block barriers (no vmcnt drain); counted vmcnt keeps prefetch in flight.
__device__ __forceinline__ void bar_fenced() {
    __builtin_amdgcn_sched_barrier(0);
    __builtin_amdgcn_s_barrier();
    __builtin_amdgcn_sched_barrier(0);
}
__device__ __forceinline__ void lgkm0_bar() {
    asm volatile("s_waitcnt lgkmcnt(0)" ::: "memory");
    __builtin_amdgcn_sched_barrier(0);
    __builtin_amdgcn_s_barrier();
    __builtin_amdgcn_sched_barrier(0);
}

struct PStage { float4 w0, w1, w2, w3, x0, x1, x2, x3; };
struct OVStage {
    f32x4u o0a, o0b, o1a, o1b;
    uint2  v0a, v0b, v1a, v1b;
};
struct AStage { uint4 k0, k1, m0, m1, p0, p1; };
struct OStage { float4 h, w; };

// ---------------------------------------------------------------------------
// Mega kernel: whole pipeline, stages separated by grid.sync (coop=1) or by
// kernel boundaries (fallback: coop=0, one launch per stage s_lo==s_hi).
// Stages: 0 conv+proj | 1 ovt | 2 mreduce | 3 attn | 4 hreduce | 5 oproj | 6 oreduce
// ---------------------------------------------------------------------------
__global__ __launch_bounds__(256, 4) void mega_kernel(
    const float* __restrict__ X,
    const float* __restrict__ Wq, const float* __restrict__ bq,
    const float* __restrict__ Wk, const float* __restrict__ bk,
    const float* __restrict__ Wv, const float* __restrict__ bvv,
    const float* __restrict__ Wo, const float* __restrict__ bo,
    const float* __restrict__ Pm, const float* __restrict__ orth,
    float* __restrict__ out, char* __restrict__ ws,
    int coop, int s_lo, int s_hi)
{
    __shared__ __align__(16) short smem[4 * 64 * 72];   // 36,864 B -> 4 blocks/CU

    // ---- workspace views (offsets all 16B-aligned) ----
    const size_t SZH = (size_t)BB * DD * TT;          // shorts per Q/K/V buffer
    short* Qb  = (short*)ws;
    short* Kb  = Qb + SZH;
    short* Vb  = Kb + SZH;
    short* Mtb = Vb + SZH;                            // [BEH*DE][TPAD] bf16
    short* Pbf = Mtb + (size_t)BEH * DE * TPAD;       // [TT][TPAD] bf16
    float* Hbuf  = (float*)(Pbf + (size_t)TT * TPAD); // [B,T,D] fp32
    float* opart = Hbuf + HSTRIDE;                    // [2][B,T,D] fp32
    float* Mpart = opart + 2 * HSTRIDE;               // [NJC][BEH*DE][TPAD] fp32
    float* Hpart = Mpart;                             // alias: Mpart dead before attn

    const int tid = threadIdx.x;
    const int bid = blockIdx.x;
    const int gtid = bid * NTHR + tid;

    const int wave = tid >> 6, lane = tid & 63;
    const int quad = lane >> 4, l16 = lane & 15;
    const int srow = tid >> 2, scg = (tid & 3) * 16;

    short (*S0)[72] = (short(*)[72])smem;
    short (*S1)[72] = (short(*)[72])(smem + 64 * 72);
    short (*S2)[72] = (short(*)[72])(smem + 2 * 64 * 72);
    short (*S3)[72] = (short(*)[72])(smem + 3 * 64 * 72);

    auto GS = [&]() {
        if (coop) { __threadfence(); cg::this_grid().sync(); }
    };
    auto DO = [&](int st) { return s_lo <= st && st <= s_hi; };

    // ================= stage 0: convp + proj =================
    if (DO(0)) {
        // --- conv: punish -> bf16 [TT][TPAD], zero pad cols ---
        for (int g = gtid; g < TT * (TPAD / 4); g += GRIDN * NTHR) {
            const int r = g / (TPAD / 4), c4 = (g - r * (TPAD / 4)) * 4;
            float p0 = 0.f, p1 = 0.f, p2 = 0.f, p3 = 0.f;
            const float* prow = Pm + (size_t)r * TT;
            if (c4 + 0 < TT) p0 = prow[c4 + 0];
            if (c4 + 1 < TT) p1 = prow[c4 + 1];
            if (c4 + 2 < TT) p2 = prow[c4 + 2];
            if (c4 + 3 < TT) p3 = prow[c4 + 3];
            uint2 o; o.x = pack2(p0, p1); o.y = pack2(p2, p3);
            *(uint2*)(Pbf + (size_t)r * TPAD + c4) = o;
        }
        // --- proj: Q/K/V = sigmoid?(X W^T + b) in [B,D,T] scramble, bf16 ---
        for (int v = bid; v < TTILES * 8 * 6; v += GRIDN) {
            const int tt = v % TTILES;
            const int rr = v / TTILES;
            const int dt = rr & 7;
            const int z  = rr >> 3;           // 0..5
            const int b = z / 3, which = z % 3;
            const float* W    = (which == 0) ? Wq : (which == 1) ? Wk : Wv;
            const float* bias = (which == 0) ? bq : (which == 1) ? bk : bvv;
            short* Y          = (which == 0) ? Qb : (which == 1) ? Kb : Vb;

            const int t0 = tt * 64, d0 = dt * 64;
            const float* Xb = X + (size_t)b * TT * DD;
            const int trow = t0 + srow;
            const int rx = min(trow, TT - 1);

            f32x4 acc[4];
            #pragma unroll
            for (int i = 0; i < 4; ++i) acc[i] = (f32x4){0.f, 0.f, 0.f, 0.f};

            auto stage = [&](PStage& S, int k0) {
                const float* wrow = W + (size_t)(d0 + srow) * DD + k0 + scg;
                S.w0 = *(const float4*)(wrow);
                S.w1 = *(const float4*)(wrow + 4);
                S.w2 = *(const float4*)(wrow + 8);
                S.w3 = *(const float4*)(wrow + 12);
                const float* xrow = Xb + (size_t)rx * DD + k0 + scg;
                S.x0 = *(const float4*)(xrow);
                S.x1 = *(const float4*)(xrow + 4);
                S.x2 = *(const float4*)(xrow + 8);
                S.x3 = *(const float4*)(xrow + 12);
            };
            auto lds_write = [&](const PStage& S) {
                const bool tv = (trow < TT);
                float4 zz = make_float4(0.f, 0.f, 0.f, 0.f);
                float4 y0 = tv ? S.x0 : zz, y1 = tv ? S.x1 : zz;
                float4 y2 = tv ? S.x2 : zz, y3 = tv ? S.x3 : zz;
                uint4 pw0, pw1, px0, px1;
                pw0.x = pack2(S.w0.x, S.w0.y); pw0.y = pack2(S.w0.z, S.w0.w);
                pw0.z = pack2(S.w1.x, S.w1.y); pw0.w = pack2(S.w1.z, S.w1.w);
                pw1.x = pack2(S.w2.x, S.w2.y); pw1.y = pack2(S.w2.z, S.w2.w);
                pw1.z = pack2(S.w3.x, S.w3.y); pw1.w = pack2(S.w3.z, S.w3.w);
                px0.x = pack2(y0.x, y0.y); px0.y = pack2(y0.z, y0.w);
                px0.z = pack2(y1.x, y1.y); px0.w = pack2(y1.z, y1.w);
                px1.x = pack2(y2.x, y2.y); px1.y = pack2(y2.z, y2.w);
                px1.z = pack2(y3.x, y3.y); px1.w = pack2(y3.z, y3.w);
                *(uint4*)&S0[srow][scg]     = pw0;
                *(uint4*)&S0[srow][scg + 8] = pw1;
                *(uint4*)&S1[srow][scg]     = px0;
                *(uint4*)&S1[srow][scg + 8] = px1;
            };
            auto mfma_tile = [&]() {
                #pragma unroll
                for (int ks = 0; ks < 2; ++ks) {
                    bf16x8 a = *(const bf16x8*)&S0[wave * 16 + l16][ks * 32 + quad * 8];
                    #pragma unroll
                    for (int nt = 0; nt < 4; ++nt) {
                        bf16x8 bb = *(const bf16x8*)&S1[nt * 16 + l16][ks * 32 + quad * 8];
                        acc[nt] = __builtin_amdgcn_mfma_f32_16x16x32_bf16(a, bb, acc[nt], 0, 0, 0);
                    }
                }
            };

            PStage sA, sB;
            stage(sA, 0);
            stage(sB, 64);
            for (int k0 = 0; k0 < DD; k0 += 128) {
                lds_write(sA);
                if (k0 + 128 < DD) stage(sA, k0 + 128);
                lgkm0_bar();
                mfma_tile();
                bar_fenced();
                lds_write(sB);
                if (k0 + 192 < DD) stage(sB, k0 + 192);
                lgkm0_bar();
                mfma_tile();
                bar_fenced();
            }

            #pragma unroll
            for (int nt = 0; nt < 4; ++nt) {
                const int t = t0 + nt * 16 + l16;
                if (t < TT) {
                    #pragma unroll
                    for (int r = 0; r < 4; ++r) {
                        const int d = d0 + wave * 16 + quad * 4 + r;
                        float vv = acc[nt][r] + bias[d];
                        if (which < 2) vv = 1.2f / (1.0f + __expf(-1.6f * vv));
                        Y[((size_t)b * DD + d) * TT + t] = f2bf(vv);
                    }
                }
            }
        }
    }
    GS();

    // ================= stage 1: ovt (Mpart) =================
    if (DO(1)) {
        for (int v = bid; v < TTILES * BEH * NJC; v += GRIDN) {
            const int sq = v % TTILES;
            const int rr = v / TTILES;
            const int be = rr & 15;
            const int jc = rr >> 4;           // 0..1
            const int s0 = sq * 64;
            const int jt0 = jc * 13, jtn = 13;

            const float* O  = orth + (size_t)be * TT * TT;
            const short* Vh = Vb + (size_t)be * DE * TT;

            const int p  = tid & 15;
            const int sc = tid >> 4;
            const int ca = s0 + 4 * sc;
            const bool fastS = (s0 + 64 <= TT);

            f32x4 acc[4];
            #pragma unroll
            for (int i = 0; i < 4; ++i) acc[i] = (f32x4){0.f, 0.f, 0.f, 0.f};

            auto stage_load = [&](OVStage& S, int j0) {
                const int jA = j0 + 2 * p;
                const int r0  = min(jA,      TT - 1);
                const int r0b = min(jA + 1,  TT - 1);
                const int r1  = min(jA + 32, TT - 1);
                const int r1b = min(jA + 33, TT - 1);
                if (fastS) {
                    S.o0a = *(const f32x4u*)(O + (size_t)r0  * TT + ca);
                    S.o0b = *(const f32x4u*)(O + (size_t)r0b * TT + ca);
                    S.o1a = *(const f32x4u*)(O + (size_t)r1  * TT + ca);
                    S.o1b = *(const f32x4u*)(O + (size_t)r1b * TT + ca);
                } else {
                    #pragma unroll
                    for (int i = 0; i < 4; ++i) {
                        const int col = ca + i;
                        const bool cv = (col < TT);
                        S.o0a[i] = cv ? O[(size_t)r0  * TT + col] : 0.f;
                        S.o0b[i] = cv ? O[(size_t)r0b * TT + col] : 0.f;
                        S.o1a[i] = cv ? O[(size_t)r1  * TT + col] : 0.f;
                        S.o1b[i] = cv ? O[(size_t)r1b * TT + col] : 0.f;
                    }
                }
                S.v0a = *(const uint2*)(Vh + (size_t)r0  * DE + 4 * sc);
                S.v0b = *(const uint2*)(Vh + (size_t)r0b * DE + 4 * sc);
                S.v1a = *(const uint2*)(Vh + (size_t)r1  * DE + 4 * sc);
                S.v1b = *(const uint2*)(Vh + (size_t)r1b * DE + 4 * sc);
            };
            auto lds_write = [&](const OVStage& S, int j0) {
                const int jA = j0 + 2 * p;
                #pragma unroll
                for (int i = 0; i < 4; ++i) {
                    *(unsigned*)&S0[4 * sc + i][2 * p]      = pack2(S.o0a[i], S.o0b[i]);
                    *(unsigned*)&S0[4 * sc + i][2 * p + 32] = pack2(S.o1a[i], S.o1b[i]);
                }
                const uint2 z = make_uint2(0u, 0u);
                uint2 v0a = (jA      < TT) ? S.v0a : z;
                uint2 v0b = (jA + 1  < TT) ? S.v0b : z;
                uint2 v1a = (jA + 32 < TT) ? S.v1a : z;
                uint2 v1b = (jA + 33 < TT) ? S.v1b : z;
                *(unsigned*)&S1[4 * sc + 0][2 * p]      = (v0a.x & 0xffffu) | (v0b.x << 16);
                *(unsigned*)&S1[4 * sc + 1][2 * p]      = (v0a.x >> 16)     | (v0b.x & 0xffff0000u);
                *(unsigned*)&S1[4 * sc + 2][2 * p]      = (v0a.y & 0xffffu) | (v0b.y << 16);
                *(unsigned*)&S1[4 * sc + 3][2 * p]      = (v0a.y >> 16)     | (v0b.y & 0xffff0000u);
                *(unsigned*)&S1[4 * sc + 0][2 * p + 32] = (v1a.x & 0xffffu) | (v1b.x << 16);
                *(unsigned*)&S1[4 * sc + 1][2 * p + 32] = (v1a.x >> 16)     | (v1b.x & 0xffff0000u);
                *(unsigned*)&S1[4 * sc + 2][2 * p + 32] = (v1a.y & 0xffffu) | (v1b.y << 16);
                *(unsigned*)&S1[4 * sc + 3][2 * p + 32] = (v1a.y >> 16)     | (v1b.y & 0xffff0000u);
            };
            auto mfma_tile = [&]() {
                #pragma unroll
                for (int ks = 0; ks < 2; ++ks) {
                    bf16x8 bb = *(const bf16x8*)&S0[wave * 16 + l16][ks * 32 + quad * 8];
                    #pragma unroll
                    for (int i = 0; i < 4; ++i) {
                        bf16x8 a = *(const bf16x8*)&S1[i * 16 + l16][ks * 32 + quad * 8];
                        acc[i] = __builtin_amdgcn_mfma_f32_16x16x32_bf16(a, bb, acc[i], 0, 0, 0);
                    }
                }
            };

            OVStage sA, sB;
            stage_load(sA, (jt0 + 0) * 64);
            stage_load(sB, (jt0 + 1) * 64);
            for (int t = 0; t < jtn; t += 2) {
                lds_write(sA, (jt0 + t) * 64);
                if (t + 2 < jtn) stage_load(sA, (jt0 + t + 2) * 64);
                lgkm0_bar();
                mfma_tile();
                bar_fenced();
                if (t + 1 < jtn) {
                    lds_write(sB, (jt0 + t + 1) * 64);
                    if (t + 3 < jtn) stage_load(sB, (jt0 + t + 3) * 64);
                    lgkm0_bar();
                    mfma_tile();
                    bar_fenced();
                }
            }

            float* Mp = Mpart + (size_t)(jc * BEH + be) * DE * MPSTRIDE;
            const int s = s0 + wave * 16 + l16;
            #pragma unroll
            for (int i = 0; i < 4; ++i) {
                #pragma unroll
                for (int r = 0; r < 4; ++r) {
                    const int d = i * 16 + quad * 4 + r;
                    Mp[(size_t)d * MPSTRIDE + s] = acc[i][r];
                }
            }
        }
    }
    GS();

    // ================= stage 2: mreduce -> Mtb bf16 =================
    if (DO(2)) {
        const size_t jstride = (size_t)BEH * DE * MPSTRIDE;
        for (int g = gtid; g < BEH * DE * (TPAD / 4); g += GRIDN * NTHR) {
            const int bd = g / (TPAD / 4);
            const int s4 = (g - bd * (TPAD / 4)) * 4;
            const float* pp = Mpart + (size_t)bd * MPSTRIDE + s4;
            float s0 = 0.f, s1 = 0.f, s2 = 0.f, s3 = 0.f;
            #pragma unroll
            for (int j = 0; j < NJC; ++j) {
                float4 a = *(const float4*)(pp + j * jstride);
                s0 += a.x; s1 += a.y; s2 += a.z; s3 += a.w;
            }
            uint2 o; o.x = pack2(s0, s1); o.y = pack2(s2, s3);
            *(uint2*)(Mtb + (size_t)bd * TPAD + s4) = o;
        }
    }
    GS();

    // ================= stage 3: attn (Hpart) =================
    if (DO(3)) {
        for (int v = bid; v < TTILES * BEH * SCN; v += GRIDN) {
            const int it = v % TTILES;
            const int rr = v / TTILES;
            const int be = rr & 15;
            const int sch = rr >> 4;          // 0..1
            const int b = be >> 3, e = be & 7;
            const int i0 = it * 64;
            const int st0 = sch * 13, stn = 13;

            const short* Qh = Qb + (size_t)be * DE * TT;
            const short* Kh = Kb + (size_t)be * DE * TT;
            const short* Mh = Mtb + (size_t)be * DE * TPAD;

            const float invs = 0.024598297f;  // 1/sqrt(1653)
            const int gi = i0 + srow;
            const bool giv = (gi < TT);
            const int ri = min(gi, TT - 1);

            {   // Q: staged once
                uint4 z = make_uint4(0u, 0u, 0u, 0u);
                uint4 v0 = *(const uint4*)(Qh + (size_t)ri * DE + scg);
                uint4 v1 = *(const uint4*)(Qh + (size_t)ri * DE + scg + 8);
                if (!giv) { v0 = z; v1 = z; }
                *(uint4*)&S0[srow][scg]     = v0;
                *(uint4*)&S0[srow][scg + 8] = v1;
            }

            f32x4 outa[4];
            #pragma unroll
            for (int i = 0; i < 4; ++i) outa[i] = (f32x4){0.f, 0.f, 0.f, 0.f};

            auto stage_regs = [&](AStage& S, int s0) {
                const int gs = s0 + srow;
                const int rs = min(gs, TT - 1);
                S.k0 = *(const uint4*)(Kh + (size_t)rs * DE + scg);
                S.k1 = *(const uint4*)(Kh + (size_t)rs * DE + scg + 8);
                S.m0 = *(const uint4*)(Mh + (size_t)srow * TPAD + s0 + scg);
                S.m1 = *(const uint4*)(Mh + (size_t)srow * TPAD + s0 + scg + 8);
                S.p0 = *(const uint4*)(Pbf + (size_t)ri * TPAD + s0 + scg);
                S.p1 = *(const uint4*)(Pbf + (size_t)ri * TPAD + s0 + scg + 8);
            };
            auto lds_write = [&](const AStage& S, int s0) {
                const int gs = s0 + srow;
                const uint4 z = make_uint4(0u, 0u, 0u, 0u);
                const bool kv = (gs < TT);
                uint4 k0 = kv ? S.k0 : z, k1 = kv ? S.k1 : z;
                uint4 p0 = giv ? S.p0 : z, p1 = giv ? S.p1 : z;
                *(uint4*)&S1[srow][scg]     = k0;
                *(uint4*)&S1[srow][scg + 8] = k1;
                *(uint4*)&S2[srow][scg]     = S.m0;
                *(uint4*)&S2[srow][scg + 8] = S.m1;
                *(uint4*)&S3[srow][scg]     = p0;
                *(uint4*)&S3[srow][scg + 8] = p1;
            };
            auto compute = [&]() {
                f32x4 w[4];
                #pragma unroll
                for (int i = 0; i < 4; ++i) w[i] = (f32x4){0.f, 0.f, 0.f, 0.f};
                #pragma unroll
                for (int ks = 0; ks < 2; ++ks) {
                    bf16x8 a = *(const bf16x8*)&S0[wave * 16 + l16][ks * 32 + quad * 8];
                    #pragma unroll
                    for (int stile = 0; stile < 4; ++stile) {
                        bf16x8 bb = *(const bf16x8*)&S1[stile * 16 + l16][ks * 32 + quad * 8];
                        w[stile] = __builtin_amdgcn_mfma_f32_16x16x32_bf16(a, bb, w[stile], 0, 0, 0);
                    }
                }
                #pragma unroll
                for (int stile = 0; stile < 4; ++stile) {
                    const int sl = stile * 16 + l16;
                    #pragma unroll
                    for (int r = 0; r < 4; ++r) {
                        const int il = wave * 16 + quad * 4 + r;
                        float vv = w[stile][r] * invs * bf2f(S3[il][sl]);
                        S3[il][sl] = f2bf(vv);
                    }
                }
                #pragma unroll
                for (int ks = 0; ks < 2; ++ks) {
                    bf16x8 a = *(const bf16x8*)&S3[wave * 16 + l16][ks * 32 + quad * 8];
                    #pragma unroll
                    for (int dt = 0; dt < 4; ++dt) {
                        bf16x8 bb = *(const bf16x8*)&S2[dt * 16 + l16][ks * 32 + quad * 8];
                        outa[dt] = __builtin_amdgcn_mfma_f32_16x16x32_bf16(a, bb, outa[dt], 0, 0, 0);
                    }
                }
            };

            AStage sA, sB;
            stage_regs(sA, (st0 + 0) * 64);
            stage_regs(sB, (st0 + 1) * 64);
            lgkm0_bar();   // Qs visible; sA/sB loads stay in flight

            for (int t = 0; t < stn; t += 2) {
                lds_write(sA, (st0 + t) * 64);
                if (t + 2 < stn) stage_regs(sA, (st0 + t + 2) * 64);
                lgkm0_bar();
                compute();
                bar_fenced();
                if (t + 1 < stn) {
                    lds_write(sB, (st0 + t + 1) * 64);
                    if (t + 3 < stn) stage_regs(sB, (st0 + t + 3) * 64);
                    lgkm0_bar();
                    compute();
                    bar_fenced();
                }
            }

            float* Hp = Hpart + (size_t)sch * HSTRIDE;
            #pragma unroll
            for (int dt = 0; dt < 4; ++dt) {
                const int d = dt * 16 + l16;
                #pragma unroll
                for (int r = 0; r < 4; ++r) {
                    const int go = i0 + wave * 16 + quad * 4 + r;
                    if (go < TT)
                        Hp[((size_t)b * TT + go) * DD + e * 64 + d] = outa[dt][r];
                }
            }
        }
    }
    GS();

    // ================= stage 4: hreduce -> Hbuf =================
    if (DO(4)) {
        const size_t n4 = HSTRIDE / 4;
        for (size_t g = gtid; g < n4; g += (size_t)GRIDN * NTHR) {
            const size_t off = g * 4;
            float4 a0 = *(const float4*)(Hpart + off);
            float4 a1 = *(const float4*)(Hpart + HSTRIDE + off);
            float4 o;
            o.x = a0.x + a1.x; o.y = a0.y + a1.y;
            o.z = a0.z + a1.z; o.w = a0.w + a1.w;
            *(float4*)(Hbuf + off) = o;
        }
    }
    GS();

    // ================= stage 5: oproj (split-k x2, fp32) =================
    if (DO(5)) {
        float (*Hs)[68] = (float(*)[68])smem;
        float (*Ns)[68] = Hs + 16;
        for (int v = bid; v < TTILES * 8 * 4; v += GRIDN) {
            const int tt = v % TTILES;
            const int rr = v / TTILES;
            const int nt = rr & 7;
            const int z  = rr >> 3;          // 0..3
            const int b = z & 1, h = z >> 1;
            const int t0 = tt * 64, n0 = nt * 64;
            const int kbase = h * 256;
            const float* Hb = Hbuf + (size_t)b * TT * DD;

            const int tx = tid & 15, ty = tid >> 4;
            const int lrow = tid >> 2, lq = tid & 3;
            const int trow = t0 + lrow;
            const int rx = min(trow, TT - 1);

            float acc[4][4] = {};

            auto stage = [&](OStage& S, int k0) {
                S.h = *(const float4*)(Hb + (size_t)rx * DD + k0 + lq * 4);
                S.w = *(const float4*)(Wo + (size_t)(n0 + lrow) * DD + k0 + lq * 4);
            };
            auto lds_write = [&](const OStage& S) {
                float4 hv = (trow < TT) ? S.h : make_float4(0.f, 0.f, 0.f, 0.f);
                Hs[lq*4+0][lrow] = hv.x; Hs[lq*4+1][lrow] = hv.y;
                Hs[lq*4+2][lrow] = hv.z; Hs[lq*4+3][lrow] = hv.w;
                Ns[lq*4+0][lrow] = S.w.x; Ns[lq*4+1][lrow] = S.w.y;
                Ns[lq*4+2][lrow] = S.w.z; Ns[lq*4+3][lrow] = S.w.w;
            };
            auto compute = [&]() {
                #pragma unroll
                for (int k = 0; k < 16; ++k) {
                    float4 a4 = *(const float4*)(&Hs[k][ty*4]);
                    float4 c4 = *(const float4*)(&Ns[k][tx*4]);
                    float a[4] = {a4.x, a4.y, a4.z, a4.w};
                    float c[4] = {c4.x, c4.y, c4.z, c4.w};
                    #pragma unroll
                    for (int i = 0; i < 4; ++i)
                        #pragma unroll
                        for (int j = 0; j < 4; ++j)
                            acc[i][j] = fmaf(a[i], c[j], acc[i][j]);
                }
            };

            OStage sA, sB;
            stage(sA, kbase);
            stage(sB, kbase + 16);
            for (int k0 = 0; k0 < 256; k0 += 32) {
                lds_write(sA);
                if (k0 + 32 < 256) stage(sA, kbase + k0 + 32);
                lgkm0_bar();
                compute();
                bar_fenced();
                lds_write(sB);
                if (k0 + 48 < 256) stage(sB, kbase + k0 + 48);
                lgkm0_bar();
                compute();
                bar_fenced();
            }

            float* op = opart + (size_t)h * HSTRIDE;
            #pragma unroll
            for (int i = 0; i < 4; ++i) {
                const int t = t0 + ty*4 + i;
                if (t < TT) {
                    float4 vv;
                    vv.x = acc[i][0]; vv.y = acc[i][1]; vv.z = acc[i][2]; vv.w = acc[i][3];
                    *(float4*)(op + ((size_t)b * TT + t) * DD + n0 + tx*4) = vv;
                }
            }
        }
    }
    GS();

    // ================= stage 6: oreduce + bias -> out =================
    if (DO(6)) {
        const size_t n4 = HSTRIDE / 4;
        for (size_t g = gtid; g < n4; g += (size_t)GRIDN * NTHR) {
            const size_t off = g * 4;
            const int n0 = (int)(off % DD);
            float4 a0 = *(const float4*)(opart + off);
            float4 a1 = *(const float4*)(opart + HSTRIDE + off);
            float4 bv4 = *(const float4*)(bo + n0);
            float4 o;
            o.x = a0.x + a1.x + bv4.x;
            o.y = a0.y + a1.y + bv4.y;
            o.z = a0.z + a1.z + bv4.z;
            o.w = a0.w + a1.w + bv4.w;
            *(float4*)(out + off) = o;
        }
    }
}

// ---------------------------------------------------------------------------
extern "C" void kernel_launch(void* const* d_in, const int* in_sizes, int n_in,
                              void* d_out, int out_size, void* d_ws, size_t ws_size,
                              hipStream_t stream)
{
    (void)in_sizes; (void)n_in; (void)out_size; (void)ws_size;

    const float* X    = (const float*)d_in[0];
    const float* Wq   = (const float*)d_in[1];
    const float* bq   = (const float*)d_in[2];
    const float* Wk   = (const float*)d_in[3];
    const float* bk   = (const float*)d_in[4];
    const float* Wv   = (const float*)d_in[5];
    const float* bvv  = (const float*)d_in[6];
    const float* Wo   = (const float*)d_in[7];
    const float* bo   = (const float*)d_in[8];
    const float* Pm   = (const float*)d_in[9];
    const float* orth = (const float*)d_in[10];
    float* outp = (float*)d_out;
    char* wsp = (char*)d_ws;

    int coop = 1, s_lo = 0, s_hi = 6;
    void* args[] = {
        (void*)&X, (void*)&Wq, (void*)&bq, (void*)&Wk, (void*)&bk,
        (void*)&Wv, (void*)&bvv, (void*)&Wo, (void*)&bo, (void*)&Pm,
        (void*)&orth, (void*)&outp, (void*)&wsp,
        (void*)&coop, (void*)&s_lo, (void*)&s_hi
    };
    hipError_t err = hipLaunchCooperativeKernel(
        (const void*)mega_kernel, dim3(GRIDN), dim3(NTHR), args, 0, stream);

    if (err != hipSuccess) {
        // Fallback: one launch per stage; kernel boundaries provide grid sync.
        for (int st = 0; st < 7; ++st) {
            mega_kernel<<<dim3(GRIDN), dim3(NTHR), 0, stream>>>(
                X, Wq, bq, Wk, bk, Wv, bvv, Wo, bo, Pm, orth,
                outp, wsp, 0, st, st);
        }
    }
}

// Round 6
// 408.270 us; speedup vs baseline: 4.6595x; 4.6595x over previous
//
#include <hip/hip_runtime.h>

// Sizes fixed by the problem.
#define TT 1653          // T
#define DD 512           // D
#define BB 2             // B
#define DE 64            // D/E
#define BEH 16           // B*E
#define TTILES 26        // ceil(T/64)
#define TPAD 1664        // T padded to multiple of 64
#define SQN 26           // ovt s-tiles (TPAD/64)
#define NJC 4            // ovt j-split
#define MPSTRIDE TPAD    // Mpart row stride (floats)

typedef __attribute__((ext_vector_type(8))) short bf16x8;   // 8 bf16 (4 VGPRs)
typedef __attribute__((ext_vector_type(4))) float f32x4;
typedef short bf16x8u __attribute__((ext_vector_type(8), aligned(4)));
typedef float f32x4u  __attribute__((ext_vector_type(4), aligned(4)));  // O rows only 4B-aligned (TT odd)

__device__ __forceinline__ short f2bf(float f) {
    union { float f; unsigned u; } v; v.f = f;
    unsigned r = v.u + 0x7fffu + ((v.u >> 16) & 1u);   // RNE
    return (short)(r >> 16);
}
__device__ __forceinline__ unsigned pack2(float a, float b) {
    return (unsigned)(unsigned short)f2bf(a) | ((unsigned)(unsigned short)f2bf(b) << 16);
}
__device__ __forceinline__ float bf2f(short s) {
    union { unsigned u; float f; } v; v.u = ((unsigned)(unsigned short)s) << 16;
    return v.f;
}
__device__ __forceinline__ bf16x8 ld_frag4(const short* p) {   // 4B-aligned LDS frag load
    bf16x8u v = *(const bf16x8u*)p;
    return (bf16x8)v;
}

// Raw barriers (no vmcnt drain); compiler emits counted vmcnt at reg uses.
__device__ __forceinline__ void bar_fenced() {
    __builtin_amdgcn_sched_barrier(0);
    __builtin_amdgcn_s_barrier();
    __builtin_amdgcn_sched_barrier(0);
}
__device__ __forceinline__ void lgkm0_bar() {
    asm volatile("s_waitcnt lgkmcnt(0)" ::: "memory");
    __builtin_amdgcn_sched_barrier(0);
    __builtin_amdgcn_s_barrier();
    __builtin_amdgcn_sched_barrier(0);
}

// ---------------------------------------------------------------------------
// Kernel 1 (MFMA): projections Q/K/V (+ fused punish-conv on the z==6 slice).
//   Y[b,d,t] = sum_k W[d,k] X[b,t,k] (+bias, sigmoid for Q/K), [B,D,T] bf16.
// ---------------------------------------------------------------------------
__global__ __launch_bounds__(256) void projconv_kernel(
    const float* __restrict__ X,
    const float* __restrict__ W0, const float* __restrict__ b0,
    const float* __restrict__ W1, const float* __restrict__ b1,
    const float* __restrict__ W2, const float* __restrict__ b2,
    const float* __restrict__ P,
    short* __restrict__ Y0, short* __restrict__ Y1, short* __restrict__ Y2,
    short* __restrict__ Pbf)
{
    __shared__ __align__(16) short Wsh[64][72];  // [d][k] bf16
    __shared__ __align__(16) short Xs[64][72];   // [t][k] bf16

    const int tid = threadIdx.x;
    const int z = blockIdx.z;

    if (z == 6) {
        // ---- conv slice: punish fp32 -> bf16 [TT][TPAD], zero pad cols ----
        const int cid = blockIdx.x + TTILES * blockIdx.y;   // 0..207
        const int NG4 = TPAD / 4;                           // 416
        for (int g = cid * 256 + tid; g < TT * NG4; g += 208 * 256) {
            const int r = g / NG4, c4 = (g - r * NG4) * 4;
            float p0 = 0.f, p1 = 0.f, p2 = 0.f, p3 = 0.f;
            const float* prow = P + (size_t)r * TT;
            if (c4 + 0 < TT) p0 = prow[c4 + 0];
            if (c4 + 1 < TT) p1 = prow[c4 + 1];
            if (c4 + 2 < TT) p2 = prow[c4 + 2];
            if (c4 + 3 < TT) p3 = prow[c4 + 3];
            uint2 o; o.x = pack2(p0, p1); o.y = pack2(p2, p3);
            *(uint2*)(Pbf + (size_t)r * TPAD + c4) = o;
        }
        return;
    }

    const int tt = blockIdx.x, dt = blockIdx.y;
    const int b = z / 3, which = z % 3;
    const float* W    = (which == 0) ? W0 : (which == 1) ? W1 : W2;
    const float* bias = (which == 0) ? b0 : (which == 1) ? b1 : b2;
    short* Y          = (which == 0) ? Y0 : (which == 1) ? Y1 : Y2;

    const int t0 = tt * 64, d0 = dt * 64;
    const float* Xb = X + (size_t)b * TT * DD;

    const int wave = tid >> 6, lane = tid & 63;
    const int quad = lane >> 4, l16 = lane & 15;
    const int srow = tid >> 2, scg = (tid & 3) * 16;
    const int trow = t0 + srow;
    const int rx = min(trow, TT - 1);

    f32x4 acc[4];
    #pragma unroll
    for (int i = 0; i < 4; ++i) acc[i] = (f32x4){0.f, 0.f, 0.f, 0.f};

    float4 w0, w1, w2, w3, x0, x1, x2, x3;

    auto stage = [&](int k0) {
        const float* wrow = W + (size_t)(d0 + srow) * DD + k0 + scg;
        w0 = *(const float4*)(wrow);
        w1 = *(const float4*)(wrow + 4);
        w2 = *(const float4*)(wrow + 8);
        w3 = *(const float4*)(wrow + 12);
        const float* xrow = Xb + (size_t)rx * DD + k0 + scg;
        x0 = *(const float4*)(xrow);
        x1 = *(const float4*)(xrow + 4);
        x2 = *(const float4*)(xrow + 8);
        x3 = *(const float4*)(xrow + 12);
    };
    auto lds_write = [&]() {
        const bool tv = (trow < TT);
        float4 zz = make_float4(0.f, 0.f, 0.f, 0.f);
        float4 y0 = tv ? x0 : zz, y1 = tv ? x1 : zz;
        float4 y2 = tv ? x2 : zz, y3 = tv ? x3 : zz;
        uint4 pw0, pw1, px0, px1;
        pw0.x = pack2(w0.x, w0.y); pw0.y = pack2(w0.z, w0.w);
        pw0.z = pack2(w1.x, w1.y); pw0.w = pack2(w1.z, w1.w);
        pw1.x = pack2(w2.x, w2.y); pw1.y = pack2(w2.z, w2.w);
        pw1.z = pack2(w3.x, w3.y); pw1.w = pack2(w3.z, w3.w);
        px0.x = pack2(y0.x, y0.y); px0.y = pack2(y0.z, y0.w);
        px0.z = pack2(y1.x, y1.y); px0.w = pack2(y1.z, y1.w);
        px1.x = pack2(y2.x, y2.y); px1.y = pack2(y2.z, y2.w);
        px1.z = pack2(y3.x, y3.y); px1.w = pack2(y3.z, y3.w);
        *(uint4*)&Wsh[srow][scg]     = pw0;
        *(uint4*)&Wsh[srow][scg + 8] = pw1;
        *(uint4*)&Xs[srow][scg]      = px0;
        *(uint4*)&Xs[srow][scg + 8]  = px1;
    };

    stage(0);
    for (int k0 = 0; k0 < DD; k0 += 64) {
        lds_write();
        if (k0 + 64 < DD) stage(k0 + 64);   // stays in flight across barriers
        lgkm0_bar();

        #pragma unroll
        for (int ks = 0; ks < 2; ++ks) {
            bf16x8 a = *(const bf16x8*)&Wsh[wave * 16 + l16][ks * 32 + quad * 8];
            #pragma unroll
            for (int nt = 0; nt < 4; ++nt) {
                bf16x8 bb = *(const bf16x8*)&Xs[nt * 16 + l16][ks * 32 + quad * 8];
                acc[nt] = __builtin_amdgcn_mfma_f32_16x16x32_bf16(a, bb, acc[nt], 0, 0, 0);
            }
        }
        bar_fenced();
    }

    #pragma unroll
    for (int nt = 0; nt < 4; ++nt) {
        const int t = t0 + nt * 16 + l16;
        if (t < TT) {
            #pragma unroll
            for (int r = 0; r < 4; ++r) {
                const int d = d0 + wave * 16 + quad * 4 + r;
                float v = acc[nt][r] + bias[d];
                if (which < 2) v = 1.2f / (1.0f + __expf(-1.6f * v));
                Y[((size_t)b * DD + d) * TT + t] = f2bf(v);
            }
        }
    }
}

// ---------------------------------------------------------------------------
// Kernel 2 (MFMA): partial Mt.  v8 — XCD-colocated + 256B-contiguous O reads.
//   Mpart[jc][be][d][s] = sum_{j in chunk jc} V[j][d] * O[j][s]
//
// T1 theory: consecutive sq blocks consume the two 64B halves of the same
// 128B lines AND the same O rows; the round-robin dispatcher was spreading
// them over 8 non-coherent L2s. Remap (bijective): xcd = flat&7 owns 8
// (be,jc) slices with all 26 sq contiguous -> same-row readers share one L2.
// Lane map swapped (p=tid>>4 rows, sc=tid&15 cols): each wave-load touches
// 4 rows x 256B contiguous (full lines). LDS stride 70 shorts (35 dwords):
// transpose writes bank = (12sc+3i+p) mod 32 -> 32 banks x 2 lanes (free);
// frag reads <=2-way. Numerically bit-identical to ovt6.
// ---------------------------------------------------------------------------
struct OVStage {
    f32x4u o0a, o0b, o1a, o1b;    // O rows j0+2p, +1, +32, +33 ; cols 4sc..+3
    uint2  v0a, v0b, v1a, v1b;    // V same rows (raw, clamped)
};

__global__ __launch_bounds__(256) void ovt8_kernel(
    const float* __restrict__ orth, const short* __restrict__ Vb,
    float* __restrict__ Mpart)
{
    __shared__ __align__(16) short Os[64][70];  // [s_local][j_local] bf16
    __shared__ __align__(16) short Vs[64][70];  // [d][j_local] bf16

    // XCD-aware bijective remap of (sq, be, jc).
    const int flat = blockIdx.x + TTILES * (blockIdx.y + BEH * blockIdx.z);
    const int xcd = flat & 7;
    const int j8  = flat >> 3;            // 0..207
    const int sq  = j8 % 26;
    const int slice = xcd * 8 + (j8 / 26);  // 0..63
    const int be = slice & 15;
    const int jc = slice >> 4;            // 0..3

    const int s0 = sq * 64;
    const int jt0 = (jc < 2) ? jc * 7 : 14 + (jc - 2) * 6;   // tiles {7,7,6,6}
    const int jtn = (jc < 2) ? 7 : 6;

    const float* O  = orth + (size_t)be * TT * TT;
    const short* Vh = Vb + (size_t)be * DE * TT;

    const int tid  = threadIdx.x;
    const int wave = tid >> 6, lane = tid & 63;
    const int quad = lane >> 4, l16 = lane & 15;

    const int p  = tid >> 4;          // j-pair index (pairs p and p+16)
    const int sc = tid & 15;          // col group: local cols 4sc..4sc+3
    const int ca = s0 + 4 * sc;       // global col base
    const bool fastS = (s0 + 64 <= TT);

    f32x4 acc[4];
    #pragma unroll
    for (int i = 0; i < 4; ++i) acc[i] = (f32x4){0.f, 0.f, 0.f, 0.f};

    auto stage_load = [&](OVStage& S, int j0) {   // raw loads only
        const int jA = j0 + 2 * p;
        const int r0  = min(jA,      TT - 1);
        const int r0b = min(jA + 1,  TT - 1);
        const int r1  = min(jA + 32, TT - 1);
        const int r1b = min(jA + 33, TT - 1);
        if (fastS) {
            S.o0a = *(const f32x4u*)(O + (size_t)r0  * TT + ca);
            S.o0b = *(const f32x4u*)(O + (size_t)r0b * TT + ca);
            S.o1a = *(const f32x4u*)(O + (size_t)r1  * TT + ca);
            S.o1b = *(const f32x4u*)(O + (size_t)r1b * TT + ca);
        } else {
            #pragma unroll
            for (int i = 0; i < 4; ++i) {
                const int col = ca + i;
                const bool cv = (col < TT);
                S.o0a[i] = cv ? O[(size_t)r0  * TT + col] : 0.f;
                S.o0b[i] = cv ? O[(size_t)r0b * TT + col] : 0.f;
                S.o1a[i] = cv ? O[(size_t)r1  * TT + col] : 0.f;
                S.o1b[i] = cv ? O[(size_t)r1b * TT + col] : 0.f;
            }
        }
        S.v0a = *(const uint2*)(Vh + (size_t)r0  * DE + 4 * sc);
        S.v0b = *(const uint2*)(Vh + (size_t)r0b * DE + 4 * sc);
        S.v1a = *(const uint2*)(Vh + (size_t)r1  * DE + 4 * sc);
        S.v1b = *(const uint2*)(Vh + (size_t)r1b * DE + 4 * sc);
    };

    auto lds_write = [&](const OVStage& S, int j0) {
        const int jA = j0 + 2 * p;
        #pragma unroll
        for (int i = 0; i < 4; ++i) {
            *(unsigned*)&Os[4 * sc + i][2 * p]      = pack2(S.o0a[i], S.o0b[i]);
            *(unsigned*)&Os[4 * sc + i][2 * p + 32] = pack2(S.o1a[i], S.o1b[i]);
        }
        const uint2 z = make_uint2(0u, 0u);
        uint2 v0a = (jA      < TT) ? S.v0a : z;
        uint2 v0b = (jA + 1  < TT) ? S.v0b : z;
        uint2 v1a = (jA + 32 < TT) ? S.v1a : z;
        uint2 v1b = (jA + 33 < TT) ? S.v1b : z;
        *(unsigned*)&Vs[4 * sc + 0][2 * p]      = (v0a.x & 0xffffu) | (v0b.x << 16);
        *(unsigned*)&Vs[4 * sc + 1][2 * p]      = (v0a.x >> 16)     | (v0b.x & 0xffff0000u);
        *(unsigned*)&Vs[4 * sc + 2][2 * p]      = (v0a.y & 0xffffu) | (v0b.y << 16);
        *(unsigned*)&Vs[4 * sc + 3][2 * p]      = (v0a.y >> 16)     | (v0b.y & 0xffff0000u);
        *(unsigned*)&Vs[4 * sc + 0][2 * p + 32] = (v1a.x & 0xffffu) | (v1b.x << 16);
        *(unsigned*)&Vs[4 * sc + 1][2 * p + 32] = (v1a.x >> 16)     | (v1b.x & 0xffff0000u);
        *(unsigned*)&Vs[4 * sc + 2][2 * p + 32] = (v1a.y & 0xffffu) | (v1b.y << 16);
        *(unsigned*)&Vs[4 * sc + 3][2 * p + 32] = (v1a.y >> 16)     | (v1b.y & 0xffff0000u);
    };

    auto mfma_tile = [&]() {
        #pragma unroll
        for (int ks = 0; ks < 2; ++ks) {
            bf16x8 bb = ld_frag4(&Os[wave * 16 + l16][ks * 32 + quad * 8]);
            #pragma unroll
            for (int i = 0; i < 4; ++i) {
                bf16x8 a = ld_frag4(&Vs[i * 16 + l16][ks * 32 + quad * 8]);
                acc[i] = __builtin_amdgcn_mfma_f32_16x16x32_bf16(a, bb, acc[i], 0, 0, 0);
            }
        }
    };

    OVStage sA, sB;
    stage_load(sA, (jt0 + 0) * 64);
    stage_load(sB, (jt0 + 1) * 64);

    for (int t = 0; t < jtn; t += 2) {
        lds_write(sA, (jt0 + t) * 64);            // compiler waits sA only
        if (t + 2 < jtn) stage_load(sA, (jt0 + t + 2) * 64);
        lgkm0_bar();
        mfma_tile();
        bar_fenced();
        if (t + 1 < jtn) {
            lds_write(sB, (jt0 + t + 1) * 64);
            if (t + 3 < jtn) stage_load(sB, (jt0 + t + 3) * 64);
            lgkm0_bar();
            mfma_tile();
            bar_fenced();
        }
    }

    // epilogue: d = i*16+quad*4+r, s = s0 + wave*16 + l16 (always < TPAD)
    float* Mp = Mpart + (size_t)(jc * BEH + be) * DE * MPSTRIDE;
    const int s = s0 + wave * 16 + l16;
    #pragma unroll
    for (int i = 0; i < 4; ++i) {
        #pragma unroll
        for (int r = 0; r < 4; ++r) {
            const int d = i * 16 + quad * 4 + r;
            Mp[(size_t)d * MPSTRIDE + s] = acc[i][r];
        }
    }
}

// ---------------------------------------------------------------------------
// Kernel 2b: reduce the 4 j-chunk partials -> bf16 Mt[be][d][TPAD].
// ---------------------------------------------------------------------------
__global__ __launch_bounds__(256) void mreduce_kernel(
    const float* __restrict__ Mpart, short* __restrict__ Mt)
{
    const int g = blockIdx.x * 256 + threadIdx.x;
    const int NG = TPAD / 4;                        // 416
    if (g >= BEH * DE * NG) return;
    const int bd = g / NG;
    const int s4 = (g - bd * NG) * 4;

    const size_t jstride = (size_t)BEH * DE * MPSTRIDE;
    const float* p = Mpart + (size_t)bd * MPSTRIDE + s4;
    float4 a0 = *(const float4*)(p);
    float4 a1 = *(const float4*)(p + jstride);
    float4 a2 = *(const float4*)(p + 2 * jstride);
    float4 a3 = *(const float4*)(p + 3 * jstride);
    float s0 = a0.x + a1.x + a2.x + a3.x;
    float s1 = a0.y + a1.y + a2.y + a3.y;
    float s2 = a0.z + a1.z + a2.z + a3.z;
    float s3 = a0.w + a1.w + a2.w + a3.w;

    uint2 o;
    o.x = pack2(s0, s1);
    o.y = pack2(s2, s3);
    *(uint2*)(Mt + (size_t)bd * TPAD + s4) = o;
}

// ---------------------------------------------------------------------------
// Kernel 3 (MFMA): fused attention. v6 — attn4 body + XCD remap (be-pairs
// colocate so each XCD's K/M working set is L2-resident).
// ---------------------------------------------------------------------------
struct AStage {
    uint4 k0, k1, m0, m1, p0, p1;
};

__global__ __launch_bounds__(256) void attn6_kernel(
    const short* __restrict__ Qb, const short* __restrict__ Kb,
    const short* __restrict__ Mt, const short* __restrict__ Pbf,
    float* __restrict__ Hbuf)
{
    __shared__ __align__(16) short Qs[64][72];  // [i][d]
    __shared__ __align__(16) short Ks[64][72];  // [s][d]
    __shared__ __align__(16) short Ms[64][72];  // [d][s]
    __shared__ __align__(16) short Ps[64][72];  // [i][s]: punish tile, then Wl

    // XCD-aware bijective remap of (it, be): xcd owns be pair {2x, 2x+1}.
    const int flat = blockIdx.x + TTILES * blockIdx.y;   // 0..415
    const int xcd = flat & 7;
    const int j8  = flat >> 3;        // 0..51
    const int it  = j8 % 26;
    const int be  = xcd * 2 + (j8 / 26);

    const int b = be >> 3, e = be & 7;
    const int i0 = it * 64;
    const short* Qh = Qb + (size_t)be * DE * TT;
    const short* Kh = Kb + (size_t)be * DE * TT;
    const short* Mh = Mt + (size_t)be * DE * TPAD;

    const int tid  = threadIdx.x;
    const int wave = tid >> 6, lane = tid & 63;
    const int quad = lane >> 4, l16 = lane & 15;

    const float invs = 0.024598297f;  // 1/sqrt(1653)

    const int srow = tid >> 2, scg = (tid & 3) * 16;
    const int gi = i0 + srow;
    const bool giv = (gi < TT);
    const int ri = min(gi, TT - 1);

    {   // Q: staged once
        uint4 z = make_uint4(0u, 0u, 0u, 0u);
        uint4 v0 = *(const uint4*)(Qh + (size_t)ri * DE + scg);
        uint4 v1 = *(const uint4*)(Qh + (size_t)ri * DE + scg + 8);
        if (!giv) { v0 = z; v1 = z; }
        *(uint4*)&Qs[srow][scg]     = v0;
        *(uint4*)&Qs[srow][scg + 8] = v1;
    }

    f32x4 out[4];
    #pragma unroll
    for (int i = 0; i < 4; ++i) out[i] = (f32x4){0.f, 0.f, 0.f, 0.f};

    auto stage_regs = [&](AStage& S, int s0) {   // raw clamped loads only
        const int gs = s0 + srow;
        const int rs = min(gs, TT - 1);
        S.k0 = *(const uint4*)(Kh + (size_t)rs * DE + scg);
        S.k1 = *(const uint4*)(Kh + (size_t)rs * DE + scg + 8);
        S.m0 = *(const uint4*)(Mh + (size_t)srow * TPAD + s0 + scg);
        S.m1 = *(const uint4*)(Mh + (size_t)srow * TPAD + s0 + scg + 8);
        S.p0 = *(const uint4*)(Pbf + (size_t)ri * TPAD + s0 + scg);
        S.p1 = *(const uint4*)(Pbf + (size_t)ri * TPAD + s0 + scg + 8);
    };

    auto lds_write = [&](const AStage& S, int s0) {
        const int gs = s0 + srow;
        const uint4 z = make_uint4(0u, 0u, 0u, 0u);
        const bool kv = (gs < TT);
        uint4 k0 = kv ? S.k0 : z, k1 = kv ? S.k1 : z;
        uint4 p0 = giv ? S.p0 : z, p1 = giv ? S.p1 : z;
        *(uint4*)&Ks[srow][scg]     = k0;
        *(uint4*)&Ks[srow][scg + 8] = k1;
        *(uint4*)&Ms[srow][scg]     = S.m0;
        *(uint4*)&Ms[srow][scg + 8] = S.m1;
        *(uint4*)&Ps[srow][scg]     = p0;
        *(uint4*)&Ps[srow][scg + 8] = p1;
    };

    auto compute = [&]() {
        f32x4 w[4];
        #pragma unroll
        for (int i = 0; i < 4; ++i) w[i] = (f32x4){0.f, 0.f, 0.f, 0.f};
        #pragma unroll
        for (int ks = 0; ks < 2; ++ks) {
            bf16x8 a = *(const bf16x8*)&Qs[wave * 16 + l16][ks * 32 + quad * 8];
            #pragma unroll
            for (int stile = 0; stile < 4; ++stile) {
                bf16x8 bb = *(const bf16x8*)&Ks[stile * 16 + l16][ks * 32 + quad * 8];
                w[stile] = __builtin_amdgcn_mfma_f32_16x16x32_bf16(a, bb, w[stile], 0, 0, 0);
            }
        }

        // scale by punish, write Wl back into the Ps buffer (wave-private rows)
        #pragma unroll
        for (int stile = 0; stile < 4; ++stile) {
            const int sl = stile * 16 + l16;
            #pragma unroll
            for (int r = 0; r < 4; ++r) {
                const int il = wave * 16 + quad * 4 + r;
                float v = w[stile][r] * invs * bf2f(Ps[il][sl]);
                Ps[il][sl] = f2bf(v);
            }
        }

        #pragma unroll
        for (int ks = 0; ks < 2; ++ks) {
            bf16x8 a = *(const bf16x8*)&Ps[wave * 16 + l16][ks * 32 + quad * 8];
            #pragma unroll
            for (int dt = 0; dt < 4; ++dt) {
                bf16x8 bb = *(const bf16x8*)&Ms[dt * 16 + l16][ks * 32 + quad * 8];
                out[dt] = __builtin_amdgcn_mfma_f32_16x16x32_bf16(a, bb, out[dt], 0, 0, 0);
            }
        }
    };

    AStage sA, sB;
    stage_regs(sA, 0);
    stage_regs(sB, 64);
    lgkm0_bar();   // Qs visible; sA/sB loads stay in flight

    for (int tt = 0; tt < TTILES; tt += 2) {
        lds_write(sA, tt * 64);                       // waits sA only
        if (tt + 2 < TTILES) stage_regs(sA, (tt + 2) * 64);
        lgkm0_bar();
        compute();
        bar_fenced();
        lds_write(sB, (tt + 1) * 64);
        if (tt + 3 < TTILES) stage_regs(sB, (tt + 3) * 64);
        lgkm0_bar();
        compute();
        bar_fenced();
    }

    #pragma unroll
    for (int dt = 0; dt < 4; ++dt) {
        const int d = dt * 16 + l16;
        #pragma unroll
        for (int r = 0; r < 4; ++r) {
            const int go = i0 + wave * 16 + quad * 4 + r;
            if (go < TT)
                Hbuf[((size_t)b * TT + go) * DD + e * 64 + d] = out[dt][r];
        }
    }
}

// ---------------------------------------------------------------------------
// Kernel 4: final projection (fp32 SGEMM, precision anchor for the output).
// ---------------------------------------------------------------------------
__global__ __launch_bounds__(256) void oproj_kernel(
    const float* __restrict__ H, const float* __restrict__ Wo,
    const float* __restrict__ bo, float* __restrict__ out)
{
    __shared__ float Hs[16][68];
    __shared__ float Ns[16][68];

    const int tt = blockIdx.x, nt = blockIdx.y, b = blockIdx.z;
    const int t0 = tt * 64, n0 = nt * 64;
    const float* Hb = H + (size_t)b * TT * DD;

    const int tid = threadIdx.x;
    const int tx = tid & 15, ty = tid >> 4;
    const int lrow = tid >> 2, lq = tid & 3;
    const int trow = t0 + lrow;

    float acc[4][4] = {};

    for (int k0 = 0; k0 < DD; k0 += 16) {
        float4 hv = make_float4(0.f, 0.f, 0.f, 0.f);
        if (trow < TT)
            hv = *(const float4*)(Hb + (size_t)trow * DD + k0 + lq*4);
        float4 wv = *(const float4*)(Wo + (size_t)(n0 + lrow) * DD + k0 + lq*4);
        __syncthreads();
        Hs[lq*4+0][lrow] = hv.x; Hs[lq*4+1][lrow] = hv.y;
        Hs[lq*4+2][lrow] = hv.z; Hs[lq*4+3][lrow] = hv.w;
        Ns[lq*4+0][lrow] = wv.x; Ns[lq*4+1][lrow] = wv.y;
        Ns[lq*4+2][lrow] = wv.z; Ns[lq*4+3][lrow] = wv.w;
        __syncthreads();
        #pragma unroll
        for (int k = 0; k < 16; ++k) {
            float4 a4 = *(const float4*)(&Hs[k][ty*4]);
            float4 c4 = *(const float4*)(&Ns[k][tx*4]);
            float a[4] = {a4.x, a4.y, a4.z, a4.w};
            float c[4] = {c4.x, c4.y, c4.z, c4.w};
            #pragma unroll
            for (int i = 0; i < 4; ++i)
                #pragma unroll
                for (int j = 0; j < 4; ++j)
                    acc[i][j] = fmaf(a[i], c[j], acc[i][j]);
        }
        __syncthreads();
    }

    #pragma unroll
    for (int i = 0; i < 4; ++i) {
        const int t = t0 + ty*4 + i;
        if (t < TT) {
            float4 v;
            v.x = acc[i][0] + bo[n0 + tx*4 + 0];
            v.y = acc[i][1] + bo[n0 + tx*4 + 1];
            v.z = acc[i][2] + bo[n0 + tx*4 + 2];
            v.w = acc[i][3] + bo[n0 + tx*4 + 3];
            *(float4*)(out + ((size_t)b * TT + t) * DD + n0 + tx*4) = v;
        }
    }
}

// ---------------------------------------------------------------------------
extern "C" void kernel_launch(void* const* d_in, const int* in_sizes, int n_in,
                              void* d_out, int out_size, void* d_ws, size_t ws_size,
                              hipStream_t stream)
{
    (void)in_sizes; (void)n_in; (void)out_size; (void)ws_size;

    const float* X    = (const float*)d_in[0];
    const float* Wq   = (const float*)d_in[1];
    const float* bq   = (const float*)d_in[2];
    const float* Wk   = (const float*)d_in[3];
    const float* bk   = (const float*)d_in[4];
    const float* Wv   = (const float*)d_in[5];
    const float* bv   = (const float*)d_in[6];
    const float* Wo   = (const float*)d_in[7];
    const float* bo   = (const float*)d_in[8];
    const float* P    = (const float*)d_in[9];
    const float* orth = (const float*)d_in[10];
    float* out = (float*)d_out;

    // Workspace layout (~46.3 MB):
    //   Qb/Kb/Vb bf16 [B*D*T]        3 x 3,385,344 B
    //   Mtb      bf16 [BE*64*TPAD]       3,407,872 B
    //   Pbf      bf16 [T*TPAD]           5,501,184 B
    //   Mpart    fp32 [4][BE*64][TPAD]  27,262,976 B  (dead after mreduce)
    //   Hbuf     fp32 [B*T*D] -- ALIASES Mpart (written by attn after mreduce)
    char* ws = (char*)d_ws;
    const size_t SZH = (size_t)BB * DD * TT * sizeof(short);
    short* Qb  = (short*)(ws);
    short* Kb  = (short*)(ws + SZH);
    short* Vb  = (short*)(ws + 2 * SZH);
    short* Mtb = (short*)(ws + 3 * SZH);
    short* Pbf = (short*)(ws + 3 * SZH + (size_t)BEH * DE * TPAD * sizeof(short));
    char*  after_p = ws + 3 * SZH + (size_t)BEH * DE * TPAD * sizeof(short)
                        + (size_t)TT * TPAD * sizeof(short);
    float* Mpart = (float*)after_p;
    float* Hbuf  = (float*)after_p;   // alias: Mpart dead before attn runs

    dim3 blk(256);

    dim3 g1(TTILES, DD / 64, BB * 3 + 1);   // z==6: fused punish conv
    projconv_kernel<<<g1, blk, 0, stream>>>(X, Wq, bq, Wk, bk, Wv, bv, P,
                                            Qb, Kb, Vb, Pbf);

    dim3 g2(SQN, BEH, NJC);
    ovt8_kernel<<<g2, blk, 0, stream>>>(orth, Vb, Mpart);

    dim3 gr((BEH * DE * (TPAD / 4) + 255) / 256);
    mreduce_kernel<<<gr, blk, 0, stream>>>(Mpart, Mtb);

    dim3 g3(TTILES, BEH);
    attn6_kernel<<<g3, blk, 0, stream>>>(Qb, Kb, Mtb, Pbf, Hbuf);

    dim3 g4(TTILES, DD / 64, BB);
    oproj_kernel<<<g4, blk, 0, stream>>>(Hbuf, Wo, bo, out);
}

// Round 7
// 390.902 us; speedup vs baseline: 4.8665x; 1.0444x over previous
//
#include <hip/hip_runtime.h>

// Sizes fixed by the problem.
#define TT 1653          // T
#define DD 512           // D
#define BB 2             // B
#define DE 64            // D/E
#define BEH 16           // B*E
#define TTILES 26        // ceil(T/64)
#define TPAD 1664        // T padded to multiple of 64
#define SQN 26           // ovt s-tiles (TPAD/64)
#define NJC 4            // ovt j-split
#define MPSTRIDE TPAD    // Mpart row stride (floats)

typedef __attribute__((ext_vector_type(8))) short bf16x8;   // 8 bf16 (4 VGPRs)
typedef __attribute__((ext_vector_type(4))) float f32x4;
typedef short bf16x8u __attribute__((ext_vector_type(8), aligned(4)));
typedef float f32x4u  __attribute__((ext_vector_type(4), aligned(4)));  // O rows only 4B-aligned (TT odd)

__device__ __forceinline__ short f2bf(float f) {
    union { float f; unsigned u; } v; v.f = f;
    unsigned r = v.u + 0x7fffu + ((v.u >> 16) & 1u);   // RNE
    return (short)(r >> 16);
}
__device__ __forceinline__ unsigned pack2(float a, float b) {
    return (unsigned)(unsigned short)f2bf(a) | ((unsigned)(unsigned short)f2bf(b) << 16);
}
__device__ __forceinline__ float bf2f(short s) {
    union { unsigned u; float f; } v; v.u = ((unsigned)(unsigned short)s) << 16;
    return v.f;
}
__device__ __forceinline__ bf16x8 ld_frag4(const short* p) {   // 4B-aligned LDS frag load
    bf16x8u v = *(const bf16x8u*)p;
    return (bf16x8)v;
}

// Raw barriers (no vmcnt drain); compiler emits counted vmcnt at reg uses.
__device__ __forceinline__ void bar_fenced() {
    __builtin_amdgcn_sched_barrier(0);
    __builtin_amdgcn_s_barrier();
    __builtin_amdgcn_sched_barrier(0);
}
__device__ __forceinline__ void lgkm0_bar() {
    asm volatile("s_waitcnt lgkmcnt(0)" ::: "memory");
    __builtin_amdgcn_sched_barrier(0);
    __builtin_amdgcn_s_barrier();
    __builtin_amdgcn_sched_barrier(0);
}

// ---------------------------------------------------------------------------
// Kernel 0 (prep): one memory-bound pass that converts
//   X   fp32 [B,T,D]  -> Xb16 bf16 [B,T,D]
//   Wq/Wk/Wv fp32 [D,D] -> bf16 [D,D]
//   punish fp32 [T,T] -> Pbf bf16 [T][TPAD] (zero pad cols)
// Hoists all fp32->bf16 rounding out of proj's 26x re-read loop: proj staging
// traffic halves and the per-tile pack2 VALU work disappears. Numerically
// identical to converting per-tile (same RNE on same values).
// ---------------------------------------------------------------------------
__global__ __launch_bounds__(256) void prep_kernel(
    const float* __restrict__ X,
    const float* __restrict__ Wq, const float* __restrict__ Wk,
    const float* __restrict__ Wv, const float* __restrict__ P,
    short* __restrict__ Xb16,
    short* __restrict__ Wqb, short* __restrict__ Wkb, short* __restrict__ Wvb,
    short* __restrict__ Pbf)
{
    const int NX4 = (BB * TT * DD) / 4;       // 423168
    const int NW4 = (DD * DD) / 4;            // 65536
    const int NP4 = TT * (TPAD / 4);          // 687648
    const int total = NX4 + 3 * NW4 + NP4;
    const int stride = gridDim.x * 256;

    for (int g = blockIdx.x * 256 + threadIdx.x; g < total; g += stride) {
        if (g < NX4 + 3 * NW4) {
            const float* src; short* dst; int idx4;
            if (g < NX4)                { src = X;  dst = Xb16; idx4 = g; }
            else if (g < NX4 + NW4)     { src = Wq; dst = Wqb;  idx4 = g - NX4; }
            else if (g < NX4 + 2 * NW4) { src = Wk; dst = Wkb;  idx4 = g - NX4 - NW4; }
            else                        { src = Wv; dst = Wvb;  idx4 = g - NX4 - 2 * NW4; }
            float4 a = *(const float4*)(src + (size_t)idx4 * 4);
            uint2 o; o.x = pack2(a.x, a.y); o.y = pack2(a.z, a.w);
            *(uint2*)(dst + (size_t)idx4 * 4) = o;
        } else {
            const int gp = g - (NX4 + 3 * NW4);
            const int r = gp / (TPAD / 4), c4 = (gp - r * (TPAD / 4)) * 4;
            float p0 = 0.f, p1 = 0.f, p2 = 0.f, p3 = 0.f;
            const float* prow = P + (size_t)r * TT;
            if (c4 + 0 < TT) p0 = prow[c4 + 0];
            if (c4 + 1 < TT) p1 = prow[c4 + 1];
            if (c4 + 2 < TT) p2 = prow[c4 + 2];
            if (c4 + 3 < TT) p3 = prow[c4 + 3];
            uint2 o; o.x = pack2(p0, p1); o.y = pack2(p2, p3);
            *(uint2*)(Pbf + (size_t)r * TPAD + c4) = o;
        }
    }
}

// ---------------------------------------------------------------------------
// Kernel 1 (MFMA): projections from pre-converted bf16 inputs.
//   Y[b,d,t] = sum_k W[d,k] X[b,t,k] (+bias, sigmoid for Q/K), [B,D,T] bf16.
// Staging is now plain uint4 bf16 copies (half the bytes, no pack VALU).
// ---------------------------------------------------------------------------
__global__ __launch_bounds__(256) void proj7_kernel(
    const short* __restrict__ Xb16,
    const short* __restrict__ W0b, const float* __restrict__ b0,
    const short* __restrict__ W1b, const float* __restrict__ b1,
    const short* __restrict__ W2b, const float* __restrict__ b2,
    short* __restrict__ Y0, short* __restrict__ Y1, short* __restrict__ Y2)
{
    __shared__ __align__(16) short Wsh[64][72];  // [d][k] bf16
    __shared__ __align__(16) short Xs[64][72];   // [t][k] bf16

    const int tt = blockIdx.x, dt = blockIdx.y, z = blockIdx.z;
    const int b = z / 3, which = z % 3;
    const short* W    = (which == 0) ? W0b : (which == 1) ? W1b : W2b;
    const float* bias = (which == 0) ? b0 : (which == 1) ? b1 : b2;
    short* Y          = (which == 0) ? Y0 : (which == 1) ? Y1 : Y2;

    const int t0 = tt * 64, d0 = dt * 64;
    const short* Xb = Xb16 + (size_t)b * TT * DD;

    const int tid  = threadIdx.x;
    const int wave = tid >> 6, lane = tid & 63;
    const int quad = lane >> 4, l16 = lane & 15;
    const int srow = tid >> 2, scg = (tid & 3) * 16;
    const int trow = t0 + srow;
    const int rx = min(trow, TT - 1);

    f32x4 acc[4];
    #pragma unroll
    for (int i = 0; i < 4; ++i) acc[i] = (f32x4){0.f, 0.f, 0.f, 0.f};

    uint4 wlo, whi, xlo, xhi;

    auto stage = [&](int k0) {   // raw bf16 tile loads
        const short* wrow = W + (size_t)(d0 + srow) * DD + k0 + scg;
        wlo = *(const uint4*)(wrow);
        whi = *(const uint4*)(wrow + 8);
        const short* xrow = Xb + (size_t)rx * DD + k0 + scg;
        xlo = *(const uint4*)(xrow);
        xhi = *(const uint4*)(xrow + 8);
    };
    auto lds_write = [&]() {
        const uint4 z4 = make_uint4(0u, 0u, 0u, 0u);
        const bool tv = (trow < TT);
        uint4 y0 = tv ? xlo : z4, y1 = tv ? xhi : z4;
        *(uint4*)&Wsh[srow][scg]     = wlo;
        *(uint4*)&Wsh[srow][scg + 8] = whi;
        *(uint4*)&Xs[srow][scg]      = y0;
        *(uint4*)&Xs[srow][scg + 8]  = y1;
    };

    stage(0);
    for (int k0 = 0; k0 < DD; k0 += 64) {
        lds_write();
        if (k0 + 64 < DD) stage(k0 + 64);   // stays in flight across barriers
        lgkm0_bar();

        #pragma unroll
        for (int ks = 0; ks < 2; ++ks) {
            bf16x8 a = *(const bf16x8*)&Wsh[wave * 16 + l16][ks * 32 + quad * 8];
            #pragma unroll
            for (int nt = 0; nt < 4; ++nt) {
                bf16x8 bb = *(const bf16x8*)&Xs[nt * 16 + l16][ks * 32 + quad * 8];
                acc[nt] = __builtin_amdgcn_mfma_f32_16x16x32_bf16(a, bb, acc[nt], 0, 0, 0);
            }
        }
        bar_fenced();
    }

    #pragma unroll
    for (int nt = 0; nt < 4; ++nt) {
        const int t = t0 + nt * 16 + l16;
        if (t < TT) {
            #pragma unroll
            for (int r = 0; r < 4; ++r) {
                const int d = d0 + wave * 16 + quad * 4 + r;
                float v = acc[nt][r] + bias[d];
                if (which < 2) v = 1.2f / (1.0f + __expf(-1.6f * v));
                Y[((size_t)b * DD + d) * TT + t] = f2bf(v);
            }
        }
    }
}

// ---------------------------------------------------------------------------
// Kernel 2 (MFMA): partial Mt.  v8 (unchanged from R6): XCD-colocated,
// 256B-contiguous O reads, stride-70 LDS, raw counted barriers.
//   Mpart[jc][be][d][s] = sum_{j in chunk jc} V[j][d] * O[j][s]
// ---------------------------------------------------------------------------
struct OVStage {
    f32x4u o0a, o0b, o1a, o1b;    // O rows j0+2p, +1, +32, +33 ; cols 4sc..+3
    uint2  v0a, v0b, v1a, v1b;    // V same rows (raw, clamped)
};

__global__ __launch_bounds__(256) void ovt8_kernel(
    const float* __restrict__ orth, const short* __restrict__ Vb,
    float* __restrict__ Mpart)
{
    __shared__ __align__(16) short Os[64][70];  // [s_local][j_local] bf16
    __shared__ __align__(16) short Vs[64][70];  // [d][j_local] bf16

    // XCD-aware bijective remap of (sq, be, jc).
    const int flat = blockIdx.x + TTILES * (blockIdx.y + BEH * blockIdx.z);
    const int xcd = flat & 7;
    const int j8  = flat >> 3;            // 0..207
    const int sq  = j8 % 26;
    const int slice = xcd * 8 + (j8 / 26);  // 0..63
    const int be = slice & 15;
    const int jc = slice >> 4;            // 0..3

    const int s0 = sq * 64;
    const int jt0 = (jc < 2) ? jc * 7 : 14 + (jc - 2) * 6;   // tiles {7,7,6,6}
    const int jtn = (jc < 2) ? 7 : 6;

    const float* O  = orth + (size_t)be * TT * TT;
    const short* Vh = Vb + (size_t)be * DE * TT;

    const int tid  = threadIdx.x;
    const int wave = tid >> 6, lane = tid & 63;
    const int quad = lane >> 4, l16 = lane & 15;

    const int p  = tid >> 4;          // j-pair index (pairs p and p+16)
    const int sc = tid & 15;          // col group: local cols 4sc..4sc+3
    const int ca = s0 + 4 * sc;       // global col base
    const bool fastS = (s0 + 64 <= TT);

    f32x4 acc[4];
    #pragma unroll
    for (int i = 0; i < 4; ++i) acc[i] = (f32x4){0.f, 0.f, 0.f, 0.f};

    auto stage_load = [&](OVStage& S, int j0) {   // raw loads only
        const int jA = j0 + 2 * p;
        const int r0  = min(jA,      TT - 1);
        const int r0b = min(jA + 1,  TT - 1);
        const int r1  = min(jA + 32, TT - 1);
        const int r1b = min(jA + 33, TT - 1);
        if (fastS) {
            S.o0a = *(const f32x4u*)(O + (size_t)r0  * TT + ca);
            S.o0b = *(const f32x4u*)(O + (size_t)r0b * TT + ca);
            S.o1a = *(const f32x4u*)(O + (size_t)r1  * TT + ca);
            S.o1b = *(const f32x4u*)(O + (size_t)r1b * TT + ca);
        } else {
            #pragma unroll
            for (int i = 0; i < 4; ++i) {
                const int col = ca + i;
                const bool cv = (col < TT);
                S.o0a[i] = cv ? O[(size_t)r0  * TT + col] : 0.f;
                S.o0b[i] = cv ? O[(size_t)r0b * TT + col] : 0.f;
                S.o1a[i] = cv ? O[(size_t)r1  * TT + col] : 0.f;
                S.o1b[i] = cv ? O[(size_t)r1b * TT + col] : 0.f;
            }
        }
        S.v0a = *(const uint2*)(Vh + (size_t)r0  * DE + 4 * sc);
        S.v0b = *(const uint2*)(Vh + (size_t)r0b * DE + 4 * sc);
        S.v1a = *(const uint2*)(Vh + (size_t)r1  * DE + 4 * sc);
        S.v1b = *(const uint2*)(Vh + (size_t)r1b * DE + 4 * sc);
    };

    auto lds_write = [&](const OVStage& S, int j0) {
        const int jA = j0 + 2 * p;
        #pragma unroll
        for (int i = 0; i < 4; ++i) {
            *(unsigned*)&Os[4 * sc + i][2 * p]      = pack2(S.o0a[i], S.o0b[i]);
            *(unsigned*)&Os[4 * sc + i][2 * p + 32] = pack2(S.o1a[i], S.o1b[i]);
        }
        const uint2 z = make_uint2(0u, 0u);
        uint2 v0a = (jA      < TT) ? S.v0a : z;
        uint2 v0b = (jA + 1  < TT) ? S.v0b : z;
        uint2 v1a = (jA + 32 < TT) ? S.v1a : z;
        uint2 v1b = (jA + 33 < TT) ? S.v1b : z;
        *(unsigned*)&Vs[4 * sc + 0][2 * p]      = (v0a.x & 0xffffu) | (v0b.x << 16);
        *(unsigned*)&Vs[4 * sc + 1][2 * p]      = (v0a.x >> 16)     | (v0b.x & 0xffff0000u);
        *(unsigned*)&Vs[4 * sc + 2][2 * p]      = (v0a.y & 0xffffu) | (v0b.y << 16);
        *(unsigned*)&Vs[4 * sc + 3][2 * p]      = (v0a.y >> 16)     | (v0b.y & 0xffff0000u);
        *(unsigned*)&Vs[4 * sc + 0][2 * p + 32] = (v1a.x & 0xffffu) | (v1b.x << 16);
        *(unsigned*)&Vs[4 * sc + 1][2 * p + 32] = (v1a.x >> 16)     | (v1b.x & 0xffff0000u);
        *(unsigned*)&Vs[4 * sc + 2][2 * p + 32] = (v1a.y & 0xffffu) | (v1b.y << 16);
        *(unsigned*)&Vs[4 * sc + 3][2 * p + 32] = (v1a.y >> 16)     | (v1b.y & 0xffff0000u);
    };

    auto mfma_tile = [&]() {
        #pragma unroll
        for (int ks = 0; ks < 2; ++ks) {
            bf16x8 bb = ld_frag4(&Os[wave * 16 + l16][ks * 32 + quad * 8]);
            #pragma unroll
            for (int i = 0; i < 4; ++i) {
                bf16x8 a = ld_frag4(&Vs[i * 16 + l16][ks * 32 + quad * 8]);
                acc[i] = __builtin_amdgcn_mfma_f32_16x16x32_bf16(a, bb, acc[i], 0, 0, 0);
            }
        }
    };

    OVStage sA, sB;
    stage_load(sA, (jt0 + 0) * 64);
    stage_load(sB, (jt0 + 1) * 64);

    for (int t = 0; t < jtn; t += 2) {
        lds_write(sA, (jt0 + t) * 64);            // compiler waits sA only
        if (t + 2 < jtn) stage_load(sA, (jt0 + t + 2) * 64);
        lgkm0_bar();
        mfma_tile();
        bar_fenced();
        if (t + 1 < jtn) {
            lds_write(sB, (jt0 + t + 1) * 64);
            if (t + 3 < jtn) stage_load(sB, (jt0 + t + 3) * 64);
            lgkm0_bar();
            mfma_tile();
            bar_fenced();
        }
    }

    // epilogue: d = i*16+quad*4+r, s = s0 + wave*16 + l16 (always < TPAD)
    float* Mp = Mpart + (size_t)(jc * BEH + be) * DE * MPSTRIDE;
    const int s = s0 + wave * 16 + l16;
    #pragma unroll
    for (int i = 0; i < 4; ++i) {
        #pragma unroll
        for (int r = 0; r < 4; ++r) {
            const int d = i * 16 + quad * 4 + r;
            Mp[(size_t)d * MPSTRIDE + s] = acc[i][r];
        }
    }
}

// ---------------------------------------------------------------------------
// Kernel 2b: reduce the 4 j-chunk partials -> bf16 Mt[be][d][TPAD].
// ---------------------------------------------------------------------------
__global__ __launch_bounds__(256) void mreduce_kernel(
    const float* __restrict__ Mpart, short* __restrict__ Mt)
{
    const int g = blockIdx.x * 256 + threadIdx.x;
    const int NG = TPAD / 4;                        // 416
    if (g >= BEH * DE * NG) return;
    const int bd = g / NG;
    const int s4 = (g - bd * NG) * 4;

    const size_t jstride = (size_t)BEH * DE * MPSTRIDE;
    const float* p = Mpart + (size_t)bd * MPSTRIDE + s4;
    float4 a0 = *(const float4*)(p);
    float4 a1 = *(const float4*)(p + jstride);
    float4 a2 = *(const float4*)(p + 2 * jstride);
    float4 a3 = *(const float4*)(p + 3 * jstride);
    float s0 = a0.x + a1.x + a2.x + a3.x;
    float s1 = a0.y + a1.y + a2.y + a3.y;
    float s2 = a0.z + a1.z + a2.z + a3.z;
    float s3 = a0.w + a1.w + a2.w + a3.w;

    uint2 o;
    o.x = pack2(s0, s1);
    o.y = pack2(s2, s3);
    *(uint2*)(Mt + (size_t)bd * TPAD + s4) = o;
}

// ---------------------------------------------------------------------------
// Kernel 3 (MFMA): fused attention. v6 (unchanged from R6).
// ---------------------------------------------------------------------------
struct AStage {
    uint4 k0, k1, m0, m1, p0, p1;
};

__global__ __launch_bounds__(256) void attn6_kernel(
    const short* __restrict__ Qb, const short* __restrict__ Kb,
    const short* __restrict__ Mt, const short* __restrict__ Pbf,
    float* __restrict__ Hbuf)
{
    __shared__ __align__(16) short Qs[64][72];  // [i][d]
    __shared__ __align__(16) short Ks[64][72];  // [s][d]
    __shared__ __align__(16) short Ms[64][72];  // [d][s]
    __shared__ __align__(16) short Ps[64][72];  // [i][s]: punish tile, then Wl

    // XCD-aware bijective remap of (it, be): xcd owns be pair {2x, 2x+1}.
    const int flat = blockIdx.x + TTILES * blockIdx.y;   // 0..415
    const int xcd = flat & 7;
    const int j8  = flat >> 3;        // 0..51
    const int it  = j8 % 26;
    const int be  = xcd * 2 + (j8 / 26);

    const int b = be >> 3, e = be & 7;
    const int i0 = it * 64;
    const short* Qh = Qb + (size_t)be * DE * TT;
    const short* Kh = Kb + (size_t)be * DE * TT;
    const short* Mh = Mt + (size_t)be * DE * TPAD;

    const int tid  = threadIdx.x;
    const int wave = tid >> 6, lane = tid & 63;
    const int quad = lane >> 4, l16 = lane & 15;

    const float invs = 0.024598297f;  // 1/sqrt(1653)

    const int srow = tid >> 2, scg = (tid & 3) * 16;
    const int gi = i0 + srow;
    const bool giv = (gi < TT);
    const int ri = min(gi, TT - 1);

    {   // Q: staged once
        uint4 z = make_uint4(0u, 0u, 0u, 0u);
        uint4 v0 = *(const uint4*)(Qh + (size_t)ri * DE + scg);
        uint4 v1 = *(const uint4*)(Qh + (size_t)ri * DE + scg + 8);
        if (!giv) { v0 = z; v1 = z; }
        *(uint4*)&Qs[srow][scg]     = v0;
        *(uint4*)&Qs[srow][scg + 8] = v1;
    }

    f32x4 out[4];
    #pragma unroll
    for (int i = 0; i < 4; ++i) out[i] = (f32x4){0.f, 0.f, 0.f, 0.f};

    auto stage_regs = [&](AStage& S, int s0) {   // raw clamped loads only
        const int gs = s0 + srow;
        const int rs = min(gs, TT - 1);
        S.k0 = *(const uint4*)(Kh + (size_t)rs * DE + scg);
        S.k1 = *(const uint4*)(Kh + (size_t)rs * DE + scg + 8);
        S.m0 = *(const uint4*)(Mh + (size_t)srow * TPAD + s0 + scg);
        S.m1 = *(const uint4*)(Mh + (size_t)srow * TPAD + s0 + scg + 8);
        S.p0 = *(const uint4*)(Pbf + (size_t)ri * TPAD + s0 + scg);
        S.p1 = *(const uint4*)(Pbf + (size_t)ri * TPAD + s0 + scg + 8);
    };

    auto lds_write = [&](const AStage& S, int s0) {
        const int gs = s0 + srow;
        const uint4 z = make_uint4(0u, 0u, 0u, 0u);
        const bool kv = (gs < TT);
        uint4 k0 = kv ? S.k0 : z, k1 = kv ? S.k1 : z;
        uint4 p0 = giv ? S.p0 : z, p1 = giv ? S.p1 : z;
        *(uint4*)&Ks[srow][scg]     = k0;
        *(uint4*)&Ks[srow][scg + 8] = k1;
        *(uint4*)&Ms[srow][scg]     = S.m0;
        *(uint4*)&Ms[srow][scg + 8] = S.m1;
        *(uint4*)&Ps[srow][scg]     = p0;
        *(uint4*)&Ps[srow][scg + 8] = p1;
    };

    auto compute = [&]() {
        f32x4 w[4];
        #pragma unroll
        for (int i = 0; i < 4; ++i) w[i] = (f32x4){0.f, 0.f, 0.f, 0.f};
        #pragma unroll
        for (int ks = 0; ks < 2; ++ks) {
            bf16x8 a = *(const bf16x8*)&Qs[wave * 16 + l16][ks * 32 + quad * 8];
            #pragma unroll
            for (int stile = 0; stile < 4; ++stile) {
                bf16x8 bb = *(const bf16x8*)&Ks[stile * 16 + l16][ks * 32 + quad * 8];
                w[stile] = __builtin_amdgcn_mfma_f32_16x16x32_bf16(a, bb, w[stile], 0, 0, 0);
            }
        }

        // scale by punish, write Wl back into the Ps buffer (wave-private rows)
        #pragma unroll
        for (int stile = 0; stile < 4; ++stile) {
            const int sl = stile * 16 + l16;
            #pragma unroll
            for (int r = 0; r < 4; ++r) {
                const int il = wave * 16 + quad * 4 + r;
                float v = w[stile][r] * invs * bf2f(Ps[il][sl]);
                Ps[il][sl] = f2bf(v);
            }
        }

        #pragma unroll
        for (int ks = 0; ks < 2; ++ks) {
            bf16x8 a = *(const bf16x8*)&Ps[wave * 16 + l16][ks * 32 + quad * 8];
            #pragma unroll
            for (int dt = 0; dt < 4; ++dt) {
                bf16x8 bb = *(const bf16x8*)&Ms[dt * 16 + l16][ks * 32 + quad * 8];
                out[dt] = __builtin_amdgcn_mfma_f32_16x16x32_bf16(a, bb, out[dt], 0, 0, 0);
            }
        }
    };

    AStage sA, sB;
    stage_regs(sA, 0);
    stage_regs(sB, 64);
    lgkm0_bar();   // Qs visible; sA/sB loads stay in flight

    for (int tt = 0; tt < TTILES; tt += 2) {
        lds_write(sA, tt * 64);                       // waits sA only
        if (tt + 2 < TTILES) stage_regs(sA, (tt + 2) * 64);
        lgkm0_bar();
        compute();
        bar_fenced();
        lds_write(sB, (tt + 1) * 64);
        if (tt + 3 < TTILES) stage_regs(sB, (tt + 3) * 64);
        lgkm0_bar();
        compute();
        bar_fenced();
    }

    #pragma unroll
    for (int dt = 0; dt < 4; ++dt) {
        const int d = dt * 16 + l16;
        #pragma unroll
        for (int r = 0; r < 4; ++r) {
            const int go = i0 + wave * 16 + quad * 4 + r;
            if (go < TT)
                Hbuf[((size_t)b * TT + go) * DD + e * 64 + d] = out[dt][r];
        }
    }
}

// ---------------------------------------------------------------------------
// Kernel 4: final projection (fp32 SGEMM, precision anchor). v3 — double-
// buffered LDS, ONE barrier per k-step (was 3), loads issued 1 iter ahead
// under compute. fma order by ascending k preserved -> bit-identical output.
// ---------------------------------------------------------------------------
__global__ __launch_bounds__(256) void oproj3_kernel(
    const float* __restrict__ H, const float* __restrict__ Wo,
    const float* __restrict__ bo, float* __restrict__ out)
{
    __shared__ float Hs[2][16][68];
    __shared__ float Ns[2][16][68];

    const int tt = blockIdx.x, nt = blockIdx.y, b = blockIdx.z;
    const int t0 = tt * 64, n0 = nt * 64;
    const float* Hb = H + (size_t)b * TT * DD;

    const int tid = threadIdx.x;
    const int tx = tid & 15, ty = tid >> 4;
    const int lrow = tid >> 2, lq = tid & 3;
    const int trow = t0 + lrow;
    const int rx = min(trow, TT - 1);

    float acc[4][4] = {};
    float4 hv, wv;

    auto stage = [&](int k0) {   // raw clamped loads
        hv = *(const float4*)(Hb + (size_t)rx * DD + k0 + lq * 4);
        wv = *(const float4*)(Wo + (size_t)(n0 + lrow) * DD + k0 + lq * 4);
    };
    auto lds_write = [&](int buf) {
        float4 h2 = (trow < TT) ? hv : make_float4(0.f, 0.f, 0.f, 0.f);
        Hs[buf][lq*4+0][lrow] = h2.x; Hs[buf][lq*4+1][lrow] = h2.y;
        Hs[buf][lq*4+2][lrow] = h2.z; Hs[buf][lq*4+3][lrow] = h2.w;
        Ns[buf][lq*4+0][lrow] = wv.x; Ns[buf][lq*4+1][lrow] = wv.y;
        Ns[buf][lq*4+2][lrow] = wv.z; Ns[buf][lq*4+3][lrow] = wv.w;
    };

    stage(0);
    lds_write(0);
    for (int it = 0; it < 32; ++it) {
        lgkm0_bar();                     // buf[it&1] visible to all waves
        if (it + 1 < 32) stage((it + 1) * 16);   // in flight under compute
        const int cur = it & 1;
        #pragma unroll
        for (int k = 0; k < 16; ++k) {
            float4 a4 = *(const float4*)(&Hs[cur][k][ty*4]);
            float4 c4 = *(const float4*)(&Ns[cur][k][tx*4]);
            float a[4] = {a4.x, a4.y, a4.z, a4.w};
            float c[4] = {c4.x, c4.y, c4.z, c4.w};
            #pragma unroll
            for (int i = 0; i < 4; ++i)
                #pragma unroll
                for (int j = 0; j < 4; ++j)
                    acc[i][j] = fmaf(a[i], c[j], acc[i][j]);
        }
        if (it + 1 < 32) lds_write((it + 1) & 1);   // other buffer: no race
    }

    #pragma unroll
    for (int i = 0; i < 4; ++i) {
        const int t = t0 + ty*4 + i;
        if (t < TT) {
            float4 v;
            v.x = acc[i][0] + bo[n0 + tx*4 + 0];
            v.y = acc[i][1] + bo[n0 + tx*4 + 1];
            v.z = acc[i][2] + bo[n0 + tx*4 + 2];
            v.w = acc[i][3] + bo[n0 + tx*4 + 3];
            *(float4*)(out + ((size_t)b * TT + t) * DD + n0 + tx*4) = v;
        }
    }
}

// ---------------------------------------------------------------------------
extern "C" void kernel_launch(void* const* d_in, const int* in_sizes, int n_in,
                              void* d_out, int out_size, void* d_ws, size_t ws_size,
                              hipStream_t stream)
{
    (void)in_sizes; (void)n_in; (void)out_size; (void)ws_size;

    const float* X    = (const float*)d_in[0];
    const float* Wq   = (const float*)d_in[1];
    const float* bq   = (const float*)d_in[2];
    const float* Wk   = (const float*)d_in[3];
    const float* bk   = (const float*)d_in[4];
    const float* Wv   = (const float*)d_in[5];
    const float* bv   = (const float*)d_in[6];
    const float* Wo   = (const float*)d_in[7];
    const float* bo   = (const float*)d_in[8];
    const float* P    = (const float*)d_in[9];
    const float* orth = (const float*)d_in[10];
    float* out = (float*)d_out;

    // Workspace layout (~51.3 MB):
    //   Qb/Kb/Vb bf16 [B*D*T]        3 x 3,385,344 B
    //   Mtb      bf16 [BE*64*TPAD]       3,407,872 B
    //   Pbf      bf16 [T*TPAD]           5,501,184 B
    //   Xb16     bf16 [B*T*D]            3,385,344 B
    //   Wqb/Wkb/Wvb bf16 [D*D]       3 x   524,288 B
    //   Mpart    fp32 [4][BE*64][TPAD]  27,262,976 B  (dead after mreduce)
    //   Hbuf     fp32 [B*T*D] -- ALIASES Mpart (written by attn after mreduce)
    char* ws = (char*)d_ws;
    const size_t SZH = (size_t)BB * DD * TT * sizeof(short);
    const size_t SZMT = (size_t)BEH * DE * TPAD * sizeof(short);
    const size_t SZP  = (size_t)TT * TPAD * sizeof(short);
    const size_t SZW  = (size_t)DD * DD * sizeof(short);
    short* Qb   = (short*)(ws);
    short* Kb   = (short*)(ws + SZH);
    short* Vb   = (short*)(ws + 2 * SZH);
    short* Mtb  = (short*)(ws + 3 * SZH);
    short* Pbf  = (short*)(ws + 3 * SZH + SZMT);
    short* Xb16 = (short*)(ws + 3 * SZH + SZMT + SZP);
    short* Wqb  = (short*)(ws + 4 * SZH + SZMT + SZP);
    short* Wkb  = (short*)(ws + 4 * SZH + SZMT + SZP + SZW);
    short* Wvb  = (short*)(ws + 4 * SZH + SZMT + SZP + 2 * SZW);
    char*  after = ws + 4 * SZH + SZMT + SZP + 3 * SZW;
    float* Mpart = (float*)after;
    float* Hbuf  = (float*)after;   // alias: Mpart dead before attn runs

    dim3 blk(256);

    prep_kernel<<<dim3(1024), blk, 0, stream>>>(X, Wq, Wk, Wv, P,
                                                Xb16, Wqb, Wkb, Wvb, Pbf);

    dim3 g1(TTILES, DD / 64, BB * 3);
    proj7_kernel<<<g1, blk, 0, stream>>>(Xb16, Wqb, bq, Wkb, bk, Wvb, bv,
                                         Qb, Kb, Vb);

    dim3 g2(SQN, BEH, NJC);
    ovt8_kernel<<<g2, blk, 0, stream>>>(orth, Vb, Mpart);

    dim3 gr((BEH * DE * (TPAD / 4) + 255) / 256);
    mreduce_kernel<<<gr, blk, 0, stream>>>(Mpart, Mtb);

    dim3 g3(TTILES, BEH);
    attn6_kernel<<<g3, blk, 0, stream>>>(Qb, Kb, Mtb, Pbf, Hbuf);

    dim3 g4(TTILES, DD / 64, BB);
    oproj3_kernel<<<g4, blk, 0, stream>>>(Hbuf, Wo, bo, out);
}